// Round 11
// baseline (34.637 us; speedup 1.0000x reference)
//
#include <hip/hip_runtime.h>

// Lucas-Kanade optical flow v11 = v10 with the YE guard-band fix.
// v10 crashed: with RB=4, band 1 starts its pipeline at row r0-7 = -3 (and
// band NBAND-2 reads to r0+11 = 2055) but was not routed to the clamping YE
// path. Correct guard: rows [4b-7, 4b+11] in-bounds iff 2 <= b <= NBAND-3.
// Structure (unchanged from v10): RB=4, 9728 waves (4 waves/block, one 4-row
// band each, no LDS/barriers), pinned exit rows (zero exit reloads),
// prefix-doubling emit tree, XCD-chunked swizzle, 2 cols/lane -> spill-free
// 64-VGPR tier (no occupancy attributes: they pin VGPR=64 and spill).
// Derivatives unscaled (8fx, 8fy, 4ft); exact power-of-2 rescale (x2) folded
// into the final u,v.

constexpr int IH  = 2048;
constexpr int IW  = 2048;
constexpr int RAD = 7;
constexpr int WIN = 15;
constexpr int NT  = 256;              // 4 waves/block, each wave = one band
constexpr int SW  = 112;              // output columns per wave (2/lane, lanes 0..55)
constexpr int RB  = 4;                // output rows per band
constexpr int SCAN = RB + WIN - 1;    // 18 steps; product rows r0-7 .. r0+10
constexpr int NSTRIP = 19;            // 19*112 = 2128 >= 2048
constexpr int NBAND  = IH / RB;       // 512
constexpr int NGRP   = NBAND / 4;     // 128 band-groups (4 bands = 1 block)
constexpr int NXCD   = 8;
constexpr int CHUNK  = NGRP / NXCD;   // 16 groups per XCD per strip

// Per-row derived terms for this lane's 2 columns: sp = prev+next, dt = next-prev.
struct Row { float sp0, sp1, dt0, dt1; };

template<bool YE>
__device__ __forceinline__ Row load_row(const float* __restrict__ P,
                                        const float* __restrict__ N,
                                        int row, int pcb, bool lload) {
    if constexpr (YE) row = row < 0 ? 0 : (row > IH - 1 ? IH - 1 : row);
    float2 q = make_float2(0.f, 0.f), r = q;
    if (lload) {                       // false only for OOB lanes on edge strips
        const size_t off = (size_t)row * IW + pcb;
        q = *reinterpret_cast<const float2*>(P + off);   // 8B aligned (pcb even)
        r = *reinterpret_cast<const float2*>(N + off);
    }
    Row R;
    R.sp0 = q.x + r.x; R.dt0 = r.x - q.x;
    R.sp1 = q.y + r.y; R.dt1 = r.y - q.y;
    return R;
}

// Add (SUB=false) or remove (SUB=true) product-row pair (A=row r, B=row r+1).
// Lane handles product cols pcb, pcb+1; col pcb+2 terms come from lane t+1.
template<bool SUB, bool XE>
__device__ __forceinline__ void accum(float V[5][2], const Row& A, const Row& B,
                                      int t, bool ok, bool rep2) {
    const float g0 = A.sp0 + B.sp0, g1 = A.sp1 + B.sp1;  // -> 8*fx via horiz diff
    const float m0 = B.sp0 - A.sp0, m1 = B.sp1 - A.sp1;  // -> 8*fy
    const float e0 = A.dt0 + B.dt0, e1 = A.dt1 + B.dt1;  // -> 4*ft
    float g2 = __shfl(g0, t + 1);
    float m2 = __shfl(m0, t + 1);
    float e2 = __shfl(e0, t + 1);
    if constexpr (XE) {                 // right edge: replicate last column
        g2 = rep2 ? g1 : g2; m2 = rep2 ? m1 : m2; e2 = rep2 ? e1 : e2;
    }
    float fx0 = g1 - g0, fy0 = m0 + m1, ft0 = e0 + e1;
    float fx1 = g2 - g1, fy1 = m1 + m2, ft1 = e1 + e2;
    if constexpr (XE) {                 // zero products outside the image
        fx0 = ok ? fx0 : 0.f; fy0 = ok ? fy0 : 0.f; ft0 = ok ? ft0 : 0.f;
        fx1 = ok ? fx1 : 0.f; fy1 = ok ? fy1 : 0.f; ft1 = ok ? ft1 : 0.f;
    }
    if constexpr (!SUB) {
        V[0][0] += fx0 * fx0; V[1][0] += fx0 * fy0; V[2][0] += fy0 * fy0;
        V[3][0] += fx0 * ft0; V[4][0] += fy0 * ft0;
        V[0][1] += fx1 * fx1; V[1][1] += fx1 * fy1; V[2][1] += fy1 * fy1;
        V[3][1] += fx1 * ft1; V[4][1] += fy1 * ft1;
    } else {
        V[0][0] -= fx0 * fx0; V[1][0] -= fx0 * fy0; V[2][0] -= fy0 * fy0;
        V[3][0] -= fx0 * ft0; V[4][0] -= fy0 * ft0;
        V[0][1] -= fx1 * fx1; V[1][1] -= fx1 * fy1; V[2][1] -= fy1 * fy1;
        V[3][1] -= fx1 * ft1; V[4][1] -= fy1 * ft1;
    }
}

template<bool XE, bool YE>
__device__ __forceinline__ void lk_body(const float* __restrict__ P,
                                        const float* __restrict__ N,
                                        float* __restrict__ out,
                                        int c0, int r0, int t) {
    const int pcb = c0 - 8 + 2 * t;     // lane's first tracked product column (even)
    bool ok = true, rep2 = false;
    if constexpr (XE) {
        ok   = ((unsigned)pcb < (unsigned)IW);   // both owned cols in image
        rep2 = (pcb + 2 >= IW) && ok;            // col pcb+2 replicates pcb+1
    }
    const bool lload = ok;              // interior strips: uniformly true

    float V[5][2] = {};

    // entering pipeline: E0=row pr, E1=pr+1, E2=pr+2 (prefetch distance 2)
    Row E0 = load_row<YE>(P, N, r0 - 7, pcb, lload);
    Row E1 = load_row<YE>(P, N, r0 - 6, pcb, lload);
    Row E2 = load_row<YE>(P, N, r0 - 5, pcb, lload);
    // pinned exit rows: rows r0-7 .. r0-4 (X3 captured at sr==0)
    Row X0 = E0, X1 = E1, X2 = E2, X3;

    #pragma unroll
    for (int sr = 0; sr < SCAN; ++sr) { // fully unrolled: sr compile-time
        const int pr = r0 - RAD + sr;   // entering product row

        // prefetch row pr+3 (last needed entering row = r0+11 -> sr <= 15)
        Row nE;
        const bool doE = (sr <= 15);
        if (doE) nE = load_row<YE>(P, N, pr + 3, pcb, lload);

        // vertical running box sum: add entering product row
        bool enter_ok = true;
        if constexpr (YE) enter_ok = (pr >= 0) && (pr < IH);
        if (enter_ok) accum<false, XE>(V, E0, E1, t, ok, rep2);

        // subtract exiting product row (pairs of pinned rows)
        if (sr >= 15) {
            bool exit_ok = true;
            if constexpr (YE) exit_ok = (pr - WIN) >= 0;
            if (exit_ok) {
                if (sr == 15) accum<true, XE>(V, X0, X1, t, ok, rep2);
                if (sr == 16) accum<true, XE>(V, X1, X2, t, ok, rep2);
                if (sr == 17) accum<true, XE>(V, X2, X3, t, ok, rep2);
            }
        }

        // emit output row i = r0 + sr - 14
        if (sr >= WIN - 1) {
            // prefix-doubling window sums: S(t) = 16-col sum from lane t
            float a0[5], a1[5];
            #pragma unroll
            for (int p = 0; p < 5; ++p) {
                const float Pg = V[p][0] + V[p][1];        // pair sum (2 cols)
                float S = Pg + __shfl(Pg, t + 1);
                S += __shfl(S, t + 2);
                S += __shfl(S, t + 4);                     // cols pcb..pcb+15
                const float q0 = __shfl(V[p][0], t + 8);   // col pcb+16
                a0[p] = S - V[p][0];                       // cols pcb+1 .. pcb+15
                a1[p] = (S - Pg) + q0;                     // cols pcb+2 .. pcb+16
            }
            const float det0 = a0[0] * a0[2] - a0[1] * a0[1];
            const float rd0  = __builtin_amdgcn_rcpf(det0) * 2.0f;  // fold scale
            const bool  k0   = (det0 != 0.f);
            const float det1 = a1[0] * a1[2] - a1[1] * a1[1];
            const float rd1  = __builtin_amdgcn_rcpf(det1) * 2.0f;
            const bool  k1   = (det1 != 0.f);
            float2 qu, qv;
            qu.x = k0 ? (a0[2] * a0[3] - a0[1] * a0[4]) * rd0 : 0.f;
            qv.x = k0 ? (a0[0] * a0[4] - a0[1] * a0[3]) * rd0 : 0.f;
            qu.y = k1 ? (a1[2] * a1[3] - a1[1] * a1[4]) * rd1 : 0.f;
            qv.y = k1 ? (a1[0] * a1[4] - a1[1] * a1[3]) * rd1 : 0.f;

            const int i  = r0 + sr - (WIN - 1);
            const int x0 = c0 + 2 * t;
            const bool st = (2 * t < SW) && (x0 < IW);    // x0 even -> x0+1 ok too
            if (st) {
                *reinterpret_cast<float2*>(out + (size_t)i * IW + x0) = qu;
                *reinterpret_cast<float2*>(out + (size_t)IH * IW + (size_t)i * IW + x0) = qv;
            }
        }

        // slides (register renames after full unroll)
        E0 = E1; E1 = E2; if (doE) E2 = nE;
        if (sr == 0) X3 = nE;           // row r0-4: fourth pinned exit row
    }
}

__global__ __launch_bounds__(NT)   // NO occupancy attrs: they pin VGPR=64 and spill
void lk_kernel(const float* __restrict__ Pimg, const float* __restrict__ Nimg,
               float* __restrict__ out) {
    // 4 independent waves per block (one 4-row band each; no LDS, no barriers).
    // XCD-chunked swizzle: XCD (bid&7) owns 16 contiguous 4-band groups of one
    // strip -> vertical-halo re-reads hit the local L2. 2432 % 8 == 0.
    const int bid   = blockIdx.x;
    const int xcd   = bid & 7;
    const int idx   = bid >> 3;               // 0..303
    const int strip = idx / CHUNK;            // 0..18
    const int pos   = idx % CHUNK;
    const int bg    = xcd * CHUNK + pos;      // 0..127 band-group within strip
    const int wid   = threadIdx.x >> 6;       // 0..3
    const int band  = bg * 4 + wid;           // 0..511
    const int t     = threadIdx.x & 63;
    const int c0 = strip * SW;
    const int r0 = band * RB;
    const bool xe = (strip == 0) || (strip == NSTRIP - 1);
    // rows touched: [r0-7, r0+11]; in-bounds iff 2 <= band <= NBAND-3
    const bool ye = (band < 2) || (band >= NBAND - 2);    // wave-uniform
    if (!xe && !ye)      lk_body<false, false>(Pimg, Nimg, out, c0, r0, t);
    else if (xe && !ye)  lk_body<true,  false>(Pimg, Nimg, out, c0, r0, t);
    else if (!xe)        lk_body<false, true >(Pimg, Nimg, out, c0, r0, t);
    else                 lk_body<true,  true >(Pimg, Nimg, out, c0, r0, t);
}

extern "C" void kernel_launch(void* const* d_in, const int* in_sizes, int n_in,
                              void* d_out, int out_size, void* d_ws, size_t ws_size,
                              hipStream_t stream) {
    (void)in_sizes; (void)n_in; (void)d_ws; (void)ws_size; (void)out_size;
    const float* prev = (const float*)d_in[0];
    const float* nxt  = (const float*)d_in[1];
    float* out        = (float*)d_out;
    dim3 grid(NSTRIP * NGRP);                 // 2432 blocks x 4 waves = 9728 waves
    dim3 block(NT);
    hipLaunchKernelGGL(lk_kernel, grid, block, 0, stream, prev, nxt, out);
}

// Round 12
// 33.675 us; speedup vs baseline: 1.0286x; 1.0286x over previous
//
#include <hip/hip_runtime.h>

// Lucas-Kanade optical flow v12: cooperative LDS staging + register scan.
// Plateau evidence (v4/v8/v9/v11 all ~33us across different structures):
// per-wave independent float2 row streams from global = small requests +
// 2.9x intra-block re-reads + L2-latency convoys. Fix: block stages the
// 31 sp/dt rows it needs ONCE (float4 loads, one barrier), scan reads are
// conflict-free ds_read_b64 (LDS-hit latency), zero global traffic in scan.
// 4 waves/block x RB=4 rows, 2 cols/lane (spill-free 64-VGPR tier), XCD
// swizzle, prefix-doubling emit. Rows clamped at stage (no YE template).
// Derivatives unscaled (8fx,8fy,4ft); exact x2 rescale folded into u,v.

constexpr int IH  = 2048;
constexpr int IW  = 2048;
constexpr int RAD = 7;
constexpr int WIN = 15;
constexpr int NT  = 256;             // 4 waves
constexpr int RB  = 4;               // output rows per wave
constexpr int BR  = 4 * RB;          // 16 output rows per block
constexpr int SROWS = BR + WIN;      // 31 staged rows: R-7 .. R+23
constexpr int SW  = 112;             // output cols per block (2/lane, lanes 0..55)
constexpr int SCAN = RB + WIN - 1;   // 18 steps
constexpr int NSTRIP = 19;           // 19*112 = 2128 >= 2048
constexpr int NGRP  = IH / BR;       // 128 row-groups
constexpr int NXCD  = 8;
constexpr int CHUNK = NGRP / NXCD;   // 16 groups per XCD per strip

__device__ __forceinline__ int clampi(int v, int lo, int hi) {
    return v < lo ? lo : (v > hi ? hi : v);
}

struct Row { float sp0, sp1, dt0, dt1; };

// Add (SUB=false) or remove (SUB=true) product-row pair (A=row r, B=row r+1).
template<bool SUB, bool XE>
__device__ __forceinline__ void accum(float V[5][2], const Row& A, const Row& B,
                                      int t, bool ok, bool rep2) {
    const float g0 = A.sp0 + B.sp0, g1 = A.sp1 + B.sp1;  // -> 8*fx via horiz diff
    const float m0 = B.sp0 - A.sp0, m1 = B.sp1 - A.sp1;  // -> 8*fy
    const float e0 = A.dt0 + B.dt0, e1 = A.dt1 + B.dt1;  // -> 4*ft
    float g2 = __shfl(g0, t + 1);
    float m2 = __shfl(m0, t + 1);
    float e2 = __shfl(e0, t + 1);
    if constexpr (XE) {                 // right edge: replicate last column
        g2 = rep2 ? g1 : g2; m2 = rep2 ? m1 : m2; e2 = rep2 ? e1 : e2;
    }
    float fx0 = g1 - g0, fy0 = m0 + m1, ft0 = e0 + e1;
    float fx1 = g2 - g1, fy1 = m1 + m2, ft1 = e1 + e2;
    if constexpr (XE) {                 // zero products outside the image
        fx0 = ok ? fx0 : 0.f; fy0 = ok ? fy0 : 0.f; ft0 = ok ? ft0 : 0.f;
        fx1 = ok ? fx1 : 0.f; fy1 = ok ? fy1 : 0.f; ft1 = ok ? ft1 : 0.f;
    }
    if constexpr (!SUB) {
        V[0][0] += fx0 * fx0; V[1][0] += fx0 * fy0; V[2][0] += fy0 * fy0;
        V[3][0] += fx0 * ft0; V[4][0] += fy0 * ft0;
        V[0][1] += fx1 * fx1; V[1][1] += fx1 * fy1; V[2][1] += fy1 * fy1;
        V[3][1] += fx1 * ft1; V[4][1] += fy1 * ft1;
    } else {
        V[0][0] -= fx0 * fx0; V[1][0] -= fx0 * fy0; V[2][0] -= fy0 * fy0;
        V[3][0] -= fx0 * ft0; V[4][0] -= fy0 * ft0;
        V[0][1] -= fx1 * fx1; V[1][1] -= fx1 * fy1; V[2][1] -= fy1 * fy1;
        V[3][1] -= fx1 * ft1; V[4][1] -= fy1 * ft1;
    }
}

template<bool XE>
__device__ __forceinline__ void scan_body(const float2* __restrict__ sp,
                                          const float2* __restrict__ dt,
                                          float* __restrict__ out,
                                          int c0, int R, int wid, int t) {
    const int r0  = R + wid * RB;
    const int kb  = wid * RB;            // wave's base staged row (img row r0-7)
    const int pcb = c0 - 8 + 2 * t;      // lane's first tracked product column
    bool ok = true, rep2 = false;
    if constexpr (XE) {
        ok   = ((unsigned)pcb < (unsigned)IW);
        rep2 = (pcb + 2 >= IW) && ok;
    }

    auto ldrow = [&](int k) -> Row {
        const float2 a = sp[k * 64 + t];
        const float2 b = dt[k * 64 + t];
        Row r; r.sp0 = a.x; r.sp1 = a.y; r.dt0 = b.x; r.dt1 = b.y; return r;
    };

    float V[5][2] = {};
    Row A = ldrow(kb), B = ldrow(kb + 1), C = ldrow(kb + 2);

    #pragma unroll
    for (int sr = 0; sr < SCAN; ++sr) {  // fully unrolled
        const int pr = r0 - RAD + sr;    // entering product row

        // issue LDS reads early
        Row nC;
        const bool doE = (sr <= 15);     // last entering pair needs row kb+18
        if (doE) nC = ldrow(kb + sr + 3);
        Row XA, XB;
        const bool doX = (sr >= WIN);    // exit pairs: rows kb+sr-15, kb+sr-14
        if (doX) { XA = ldrow(kb + sr - 15); XB = ldrow(kb + sr - 14); }

        // vertical running box sum
        if (pr >= 0 && pr < IH)                      // wave-uniform
            accum<false, XE>(V, A, B, t, ok, rep2);
        if (doX && (pr - WIN) >= 0)
            accum<true, XE>(V, XA, XB, t, ok, rep2);

        // emit output row i = r0 + sr - 14
        if (sr >= WIN - 1) {
            float a0[5], a1[5];
            #pragma unroll
            for (int p = 0; p < 5; ++p) {
                const float Pg = V[p][0] + V[p][1];        // pair sum (2 cols)
                float S = Pg + __shfl(Pg, t + 1);
                S += __shfl(S, t + 2);
                S += __shfl(S, t + 4);                     // cols pcb..pcb+15
                const float q0 = __shfl(V[p][0], t + 8);   // col pcb+16
                a0[p] = S - V[p][0];                       // cols pcb+1 .. pcb+15
                a1[p] = (S - Pg) + q0;                     // cols pcb+2 .. pcb+16
            }
            const float det0 = a0[0] * a0[2] - a0[1] * a0[1];
            const float rd0  = __builtin_amdgcn_rcpf(det0) * 2.0f;  // fold scale
            const bool  k0   = (det0 != 0.f);
            const float det1 = a1[0] * a1[2] - a1[1] * a1[1];
            const float rd1  = __builtin_amdgcn_rcpf(det1) * 2.0f;
            const bool  k1   = (det1 != 0.f);
            float2 qu, qv;
            qu.x = k0 ? (a0[2] * a0[3] - a0[1] * a0[4]) * rd0 : 0.f;
            qv.x = k0 ? (a0[0] * a0[4] - a0[1] * a0[3]) * rd0 : 0.f;
            qu.y = k1 ? (a1[2] * a1[3] - a1[1] * a1[4]) * rd1 : 0.f;
            qv.y = k1 ? (a1[0] * a1[4] - a1[1] * a1[3]) * rd1 : 0.f;

            const int i  = r0 + sr - (WIN - 1);
            const int x0 = c0 + 2 * t;
            if ((2 * t < SW) && (x0 < IW)) {   // x0 even -> x0+1 in range too
                *reinterpret_cast<float2*>(out + (size_t)i * IW + x0) = qu;
                *reinterpret_cast<float2*>(out + (size_t)IH * IW + (size_t)i * IW + x0) = qv;
            }
        }

        A = B; B = C; if (doE) C = nC;   // slide (renamed by unroll)
    }
}

__global__ __launch_bounds__(NT)   // no occupancy attrs (they pin VGPR=64 + spill)
void lk_kernel(const float* __restrict__ Pimg, const float* __restrict__ Nimg,
               float* __restrict__ out) {
    // sp/dt planes for the block's 31 rows; float4 arrays keep 16B alignment.
    // Stage writes: linear b128 (conflict-free). Scan reads: linear b64.
    __shared__ float4 s_sp[SROWS][32];
    __shared__ float4 s_dt[SROWS][32];

    // XCD-chunked swizzle: XCD (bid&7) owns 16 contiguous 16-row groups of one
    // strip -> inter-block halo re-reads hit the local L2. 2432 % 8 == 0.
    const int bid   = blockIdx.x;
    const int xcd   = bid & 7;
    const int idx   = bid >> 3;               // 0..303
    const int strip = idx / CHUNK;            // 0..18
    const int pos   = idx % CHUNK;
    const int bg    = xcd * CHUNK + pos;      // 0..127
    const int c0    = strip * SW;
    const int R     = bg * BR;                // block's first output row

    // ---- cooperative stage: 31 rows x 128 cols of sp/dt ----
    const int jq = threadIdx.x & 31;          // col quad 0..31 (4 cols each)
    const int rr = threadIdx.x >> 5;          // 0..7 (8 rows per pass)
    const int gc = c0 - 8 + 4 * jq;           // first image col of this quad
    const bool in4 = (gc >= 0) && (gc + 3 < IW);
    #pragma unroll
    for (int k0 = 0; k0 < SROWS; k0 += 8) {
        const int k = k0 + rr;
        if (k < SROWS) {
            const int row = clampi(R - RAD + k, 0, IH - 1);
            const float* rp = Pimg + (size_t)row * IW;
            const float* rn = Nimg + (size_t)row * IW;
            float4 p, n;
            if (in4) {
                p = *reinterpret_cast<const float4*>(rp + gc);   // 16B aligned
                n = *reinterpret_cast<const float4*>(rn + gc);
            } else {                                  // edge strips only
                const int g0 = clampi(gc,     0, IW - 1);
                const int g1 = clampi(gc + 1, 0, IW - 1);
                const int g2 = clampi(gc + 2, 0, IW - 1);
                const int g3 = clampi(gc + 3, 0, IW - 1);
                p = make_float4(rp[g0], rp[g1], rp[g2], rp[g3]);
                n = make_float4(rn[g0], rn[g1], rn[g2], rn[g3]);
            }
            s_sp[k][jq] = make_float4(p.x + n.x, p.y + n.y, p.z + n.z, p.w + n.w);
            s_dt[k][jq] = make_float4(n.x - p.x, n.y - p.y, n.z - p.z, n.w - p.w);
        }
    }
    __syncthreads();

    // ---- barrier-free register scan, one 4-row band per wave ----
    const int wid = threadIdx.x >> 6;
    const int t   = threadIdx.x & 63;
    const float2* sp = reinterpret_cast<const float2*>(&s_sp[0][0]);
    const float2* dt = reinterpret_cast<const float2*>(&s_dt[0][0]);
    if (strip == 0 || strip == NSTRIP - 1)
        scan_body<true >(sp, dt, out, c0, R, wid, t);
    else
        scan_body<false>(sp, dt, out, c0, R, wid, t);
}

extern "C" void kernel_launch(void* const* d_in, const int* in_sizes, int n_in,
                              void* d_out, int out_size, void* d_ws, size_t ws_size,
                              hipStream_t stream) {
    (void)in_sizes; (void)n_in; (void)d_ws; (void)ws_size; (void)out_size;
    const float* prev = (const float*)d_in[0];
    const float* nxt  = (const float*)d_in[1];
    float* out        = (float*)d_out;
    dim3 grid(NSTRIP * NGRP);                 // 2432 blocks x 4 waves
    dim3 block(NT);
    hipLaunchKernelGGL(lk_kernel, grid, block, 0, stream, prev, nxt, out);
}

// Round 13
// 31.261 us; speedup vs baseline: 1.1080x; 1.0772x over previous
//
#include <hip/hip_runtime.h>

// Lucas-Kanade optical flow v13 = v8 with deep prefetch (the single change).
// Plateau evidence: VALU-cut, DS-cut, 2x waves, LDS staging all leave ~33us
// -> per-step load latency (issue distance ~3 steps ~ 350cyc < L3/HBM
// 400-900cyc) is the last live theory. v13 deepens both pipelines:
// entering rows E0..E5 + nE at row pr+6 (use distance 4-5 steps), exit rows
// issued 4-6 steps ahead through X0..X4. ~13 Rows live ~= 80 VGPR (no
// occupancy attrs -- they pin VGPR=64 and spill; plain launch_bounds gave
// v1 88 VGPRs). Everything else identical to v8: RB=8, 4864 one-wave
// blocks, XCD-chunked swizzle, prefix-doubling emit, 2 cols/lane.
// Derivatives unscaled (8fx, 8fy, 4ft); exact x2 rescale folded into u,v.

constexpr int IH  = 2048;
constexpr int IW  = 2048;
constexpr int RAD = 7;
constexpr int WIN = 15;
constexpr int NT  = 64;               // 1 wave per block
constexpr int SW  = 112;              // output columns per block (2/lane, lanes 0..55)
constexpr int RB  = 8;                // output rows per block
constexpr int SCAN = RB + WIN - 1;    // 22 steps; product rows r0-7 .. r0+14
constexpr int NSTRIP = 19;            // 19*112 = 2128 >= 2048
constexpr int NBAND  = IH / RB;       // 256
constexpr int NXCD   = 8;
constexpr int CHUNK  = NBAND / NXCD;  // 32 bands per XCD per strip

// Per-row derived terms for this lane's 2 columns: sp = prev+next, dt = next-prev.
struct Row { float sp0, sp1, dt0, dt1; };

template<bool YE>
__device__ __forceinline__ Row load_row(const float* __restrict__ P,
                                        const float* __restrict__ N,
                                        int row, int pcb, bool lload) {
    if constexpr (YE) row = row < 0 ? 0 : (row > IH - 1 ? IH - 1 : row);
    float2 q = make_float2(0.f, 0.f), r = q;
    if (lload) {                       // false only for OOB lanes on edge strips
        const size_t off = (size_t)row * IW + pcb;
        q = *reinterpret_cast<const float2*>(P + off);   // 8B aligned (pcb even)
        r = *reinterpret_cast<const float2*>(N + off);
    }
    Row R;
    R.sp0 = q.x + r.x; R.dt0 = r.x - q.x;
    R.sp1 = q.y + r.y; R.dt1 = r.y - q.y;
    return R;
}

// Add (SUB=false) or remove (SUB=true) product-row pair (A=row r, B=row r+1).
// Lane handles product cols pcb, pcb+1; col pcb+2 terms come from lane t+1.
template<bool SUB, bool XE>
__device__ __forceinline__ void accum(float V[5][2], const Row& A, const Row& B,
                                      int t, bool ok, bool rep2) {
    const float g0 = A.sp0 + B.sp0, g1 = A.sp1 + B.sp1;  // -> 8*fx via horiz diff
    const float m0 = B.sp0 - A.sp0, m1 = B.sp1 - A.sp1;  // -> 8*fy
    const float e0 = A.dt0 + B.dt0, e1 = A.dt1 + B.dt1;  // -> 4*ft
    float g2 = __shfl(g0, t + 1);
    float m2 = __shfl(m0, t + 1);
    float e2 = __shfl(e0, t + 1);
    if constexpr (XE) {                 // right edge: replicate last column
        g2 = rep2 ? g1 : g2; m2 = rep2 ? m1 : m2; e2 = rep2 ? e1 : e2;
    }
    float fx0 = g1 - g0, fy0 = m0 + m1, ft0 = e0 + e1;
    float fx1 = g2 - g1, fy1 = m1 + m2, ft1 = e1 + e2;
    if constexpr (XE) {                 // zero products outside the image
        fx0 = ok ? fx0 : 0.f; fy0 = ok ? fy0 : 0.f; ft0 = ok ? ft0 : 0.f;
        fx1 = ok ? fx1 : 0.f; fy1 = ok ? fy1 : 0.f; ft1 = ok ? ft1 : 0.f;
    }
    if constexpr (!SUB) {
        V[0][0] += fx0 * fx0; V[1][0] += fx0 * fy0; V[2][0] += fy0 * fy0;
        V[3][0] += fx0 * ft0; V[4][0] += fy0 * ft0;
        V[0][1] += fx1 * fx1; V[1][1] += fx1 * fy1; V[2][1] += fy1 * fy1;
        V[3][1] += fx1 * ft1; V[4][1] += fy1 * ft1;
    } else {
        V[0][0] -= fx0 * fx0; V[1][0] -= fx0 * fy0; V[2][0] -= fy0 * fy0;
        V[3][0] -= fx0 * ft0; V[4][0] -= fy0 * ft0;
        V[0][1] -= fx1 * fx1; V[1][1] -= fx1 * fy1; V[2][1] -= fy1 * fy1;
        V[3][1] -= fx1 * ft1; V[4][1] -= fy1 * ft1;
    }
}

template<bool XE, bool YE>
__device__ __forceinline__ void lk_body(const float* __restrict__ P,
                                        const float* __restrict__ N,
                                        float* __restrict__ out,
                                        int c0, int r0, int t) {
    const int pcb = c0 - 8 + 2 * t;     // lane's first tracked product column (even)
    bool ok = true, rep2 = false;
    if constexpr (XE) {
        ok   = ((unsigned)pcb < (unsigned)IW);   // both owned cols in image
        rep2 = (pcb + 2 >= IW) && ok;            // col pcb+2 replicates pcb+1
    }
    const bool lload = ok;              // interior strips: uniformly true

    float V[5][2] = {};

    // entering pipeline E0..E5 = rows r0-7 .. r0-2 (use distance 4-5 steps)
    Row E0 = load_row<YE>(P, N, r0 - 7, pcb, lload);
    Row E1 = load_row<YE>(P, N, r0 - 6, pcb, lload);
    Row E2 = load_row<YE>(P, N, r0 - 5, pcb, lload);
    Row E3 = load_row<YE>(P, N, r0 - 4, pcb, lload);
    Row E4 = load_row<YE>(P, N, r0 - 3, pcb, lload);
    Row E5 = load_row<YE>(P, N, r0 - 2, pcb, lload);
    Row X0, X1, X2, X3, X4;             // exit pipeline (issued 4-6 steps ahead)

    #pragma unroll
    for (int sr = 0; sr < SCAN; ++sr) { // fully unrolled: sr compile-time
        const int pr = r0 - RAD + sr;   // entering product row

        // issue loads first (deep prefetch)
        Row nE, nX;
        const bool doE = (sr <= 16);    // row pr+6 = r0-1+sr; last = r0+15
        if (doE) nE = load_row<YE>(P, N, pr + 6, pcb, lload);
        const bool doX = (sr >= 10 && sr <= 17);  // row r0+sr-17: r0-7 .. r0
        if (doX) nX = load_row<YE>(P, N, r0 + sr - 17, pcb, lload);

        // vertical running box sum: add entering product row (rows pr, pr+1)
        bool enter_ok = true;
        if constexpr (YE) enter_ok = (pr >= 0) && (pr < IH);
        if (enter_ok) accum<false, XE>(V, E0, E1, t, ok, rep2);

        // subtract exiting product row (rows pr-15, pr-14) = X0, X1
        if (sr >= WIN) {
            bool exit_ok = true;
            if constexpr (YE) exit_ok = (pr - WIN) >= 0;
            if (exit_ok) accum<true, XE>(V, X0, X1, t, ok, rep2);
        }

        // emit output row i = r0 + sr - 14
        if (sr >= WIN - 1) {
            // prefix-doubling window sums: S(t) = 16-col sum from lane t
            float a0[5], a1[5];
            #pragma unroll
            for (int p = 0; p < 5; ++p) {
                const float Pg = V[p][0] + V[p][1];        // pair sum (2 cols)
                float S = Pg + __shfl(Pg, t + 1);
                S += __shfl(S, t + 2);
                S += __shfl(S, t + 4);                     // cols pcb..pcb+15
                const float q0 = __shfl(V[p][0], t + 8);   // col pcb+16
                a0[p] = S - V[p][0];                       // cols pcb+1 .. pcb+15
                a1[p] = (S - Pg) + q0;                     // cols pcb+2 .. pcb+16
            }
            const float det0 = a0[0] * a0[2] - a0[1] * a0[1];
            const float rd0  = __builtin_amdgcn_rcpf(det0) * 2.0f;  // fold scale
            const bool  k0   = (det0 != 0.f);
            const float det1 = a1[0] * a1[2] - a1[1] * a1[1];
            const float rd1  = __builtin_amdgcn_rcpf(det1) * 2.0f;
            const bool  k1   = (det1 != 0.f);
            float2 qu, qv;
            qu.x = k0 ? (a0[2] * a0[3] - a0[1] * a0[4]) * rd0 : 0.f;
            qv.x = k0 ? (a0[0] * a0[4] - a0[1] * a0[3]) * rd0 : 0.f;
            qu.y = k1 ? (a1[2] * a1[3] - a1[1] * a1[4]) * rd1 : 0.f;
            qv.y = k1 ? (a1[0] * a1[4] - a1[1] * a1[3]) * rd1 : 0.f;

            const int i  = r0 + sr - (WIN - 1);
            const int x0 = c0 + 2 * t;
            if ((2 * t < SW) && (x0 < IW)) {   // x0 even -> x0+1 in range too
                *reinterpret_cast<float2*>(out + (size_t)i * IW + x0) = qu;
                *reinterpret_cast<float2*>(out + (size_t)IH * IW + (size_t)i * IW + x0) = qv;
            }
        }

        // slides (register renames after full unroll)
        E0 = E1; E1 = E2; E2 = E3; E3 = E4; E4 = E5; if (doE) E5 = nE;
        // X fill at sr=10..14, then shift with tail refills at 15..17.
        // Verified schedule: consumption at sr>=15 uses pre-slide X0,X1 =
        // rows (r0+sr-22, r0+sr-21); issue->use distance 4-6 steps.
        if (sr == 10)      X0 = nX;
        else if (sr == 11) X1 = nX;
        else if (sr == 12) X2 = nX;
        else if (sr == 13) X3 = nX;
        else if (sr == 14) X4 = nX;
        else if (sr >= 15) { X0 = X1; X1 = X2; X2 = X3; X3 = X4; if (sr <= 17) X4 = nX; }
    }
}

__global__ __launch_bounds__(NT)   // NO occupancy attrs: they pin VGPR=64 and spill
void lk_kernel(const float* __restrict__ Pimg, const float* __restrict__ Nimg,
               float* __restrict__ out) {
    // XCD-chunked swizzle (unchanged from v8): XCD (bid&7) owns 32 contiguous
    // 8-row bands of one strip -> vertical-halo re-reads hit the local L2.
    const int bid   = blockIdx.x;
    const int xcd   = bid & 7;
    const int idx   = bid >> 3;               // 0..607
    const int strip = idx / CHUNK;            // 0..18
    const int pos   = idx % CHUNK;
    const int band  = xcd * CHUNK + pos;      // 0..255
    const int c0 = strip * SW;
    const int r0 = band * RB;
    const int t  = threadIdx.x;
    const bool xe = (strip == 0) || (strip == NSTRIP - 1);
    // rows touched: [r0-7, r0+15]; in-bounds iff 1 <= band <= NBAND-2
    const bool ye = (band == 0) || (band == NBAND - 1);
    if (!xe && !ye)      lk_body<false, false>(Pimg, Nimg, out, c0, r0, t);
    else if (xe && !ye)  lk_body<true,  false>(Pimg, Nimg, out, c0, r0, t);
    else if (!xe)        lk_body<false, true >(Pimg, Nimg, out, c0, r0, t);
    else                 lk_body<true,  true >(Pimg, Nimg, out, c0, r0, t);
}

extern "C" void kernel_launch(void* const* d_in, const int* in_sizes, int n_in,
                              void* d_out, int out_size, void* d_ws, size_t ws_size,
                              hipStream_t stream) {
    (void)in_sizes; (void)n_in; (void)d_ws; (void)ws_size; (void)out_size;
    const float* prev = (const float*)d_in[0];
    const float* nxt  = (const float*)d_in[1];
    float* out        = (float*)d_out;
    dim3 grid(NSTRIP * NBAND);                // 4864 one-wave blocks
    dim3 block(NT);
    hipLaunchKernelGGL(lk_kernel, grid, block, 0, stream, prev, nxt, out);
}